// Round 15
// baseline (1358.567 us; speedup 1.0000x reference)
//
#include <hip/hip_runtime.h>
#include <hip/hip_fp16.h>

#define NT 18
#define NX 160
#define NY 160
#define NPIX (NX*NY)      // 25600
#define NVOX (NT*NPIX)    // 460800

typedef _Float16 __attribute__((ext_vector_type(2))) half2t;
typedef _Float16 __attribute__((ext_vector_type(8))) half8t;
typedef float    __attribute__((ext_vector_type(4))) f32x4;
typedef unsigned int u32;
typedef __attribute__((address_space(1))) const u32 gu32;
typedef __attribute__((address_space(3))) u32 lu32;

// ---------------------------------------------------------------------------
__global__ void probe_kernel(float* __restrict__ out, int n, float val) {
  int i = blockIdx.x * 256 + threadIdx.x;
  if (i < n) out[i] = val;
}

// ---------------------------------------------------------------------------
// DFT matrix G[u][j] = F[(u+80)%160][(j+80)%160], F = ortho DFT(160).
// fft2c(X) = G X G (G symmetric); ifft2c(X) = conj(G) X conj(G).
// ---------------------------------------------------------------------------
__global__ void make_g_kernel(float2* __restrict__ G) {
  int idx = blockIdx.x * 256 + threadIdx.x;
  if (idx >= NPIX) return;
  int r = idx / NY, c = idx - (idx / NY) * NY;
  int rs = (r + 80) % 160;
  int cs = (c + 80) % 160;
  int prod = (rs * cs) % 160;
  double ang = -2.0 * 3.14159265358979323846 * (double)prod / 160.0;
  double sc = 0.07905694150420949;  // 1/sqrt(160)
  G[idx] = make_float2((float)(cos(ang) * sc), (float)(sin(ang) * sc));
}

// ---------------------------------------------------------------------------
// FFT pass over last axis, 8 rows per block (360 blocks, XCD-chunk swizzled
// so producer/consumer of a t-slice share an XCD L2; halves G re-reads).
// MASKD=1: rows are loaded as mask*d (fuses the former mask_d kernel).
// ---------------------------------------------------------------------------
template <int MASKD>
__global__ void fft_pass_last8(const float2* __restrict__ in, float2* __restrict__ out,
                               const float2* __restrict__ G, int conjf,
                               const float* __restrict__ dr, const float* __restrict__ di,
                               const int* __restrict__ maskp) {
  __shared__ float2 rows[8][NY];
  int b = (int)blockIdx.x;
  int sb = (b & 7) * 45 + (b >> 3);   // 360 % 8 == 0 -> bijective
  int r0 = sb * 8;                    // 360 blocks * 8 = NT*NX rows
  int v = threadIdx.x;                // 0..159
#pragma unroll
  for (int r = 0; r < 8; ++r) {
    size_t idx = (size_t)(r0 + r) * NY + v;
    if (MASKD) {
      float m = (float)maskp[idx];
      rows[r][v] = make_float2(m * dr[idx], m * di[idx]);
    } else {
      rows[r][v] = in[idx];
    }
  }
  __syncthreads();
  float sgn = conjf ? -1.f : 1.f;
  float ar[8] = {0.f, 0.f, 0.f, 0.f, 0.f, 0.f, 0.f, 0.f};
  float ai[8] = {0.f, 0.f, 0.f, 0.f, 0.f, 0.f, 0.f, 0.f};
  for (int k = 0; k < NY; ++k) {
    float2 g = G[k * NY + v];
    float gi = sgn * g.y;
#pragma unroll
    for (int r = 0; r < 8; ++r) {
      float2 a = rows[r][k];
      ar[r] += a.x * g.x - a.y * gi;
      ai[r] += a.x * gi + a.y * g.x;
    }
  }
#pragma unroll
  for (int r = 0; r < 8; ++r)
    out[(size_t)(r0 + r) * NY + v] = make_float2(ar[r], ai[r]);
}

// ---------------------------------------------------------------------------
// FFT pass over middle axis, 8 u-values per block (360 blocks, XCD-swizzled).
// EPI=0: plain write.  EPI=1: fused mask_q.  EPI=2: fused rn -> Rf.
// EPI=3: fused rn, iteration 0 (beta = t = 0; no loads) — exact.
// ---------------------------------------------------------------------------
template <int EPI>
__global__ void fft_pass_mid8(const float2* __restrict__ in, void* __restrict__ outv,
                              const float2* __restrict__ G, int conjf,
                              const float* __restrict__ dr, const float* __restrict__ di,
                              const int* __restrict__ maskp,
                              const float2* __restrict__ xrec2, const float2* __restrict__ beta2,
                              const float2* __restrict__ tbuf2,
                              const float* __restrict__ l1p, const float* __restrict__ l2p) {
  __shared__ float2 grow[8][NX];
  int b = (int)blockIdx.x;
  int sb = (b & 7) * 45 + (b >> 3);     // 360 % 8 == 0 -> bijective
  int t = sb / 20;                      // 18 * 20 = 360 blocks
  int u0 = (sb - t * 20) * 8;
  int v = threadIdx.x;
#pragma unroll
  for (int r = 0; r < 8; ++r) grow[r][v] = G[(u0 + r) * NX + v];
  __syncthreads();
  float sgn = conjf ? -1.f : 1.f;
  float ar[8] = {0.f, 0.f, 0.f, 0.f, 0.f, 0.f, 0.f, 0.f};
  float ai[8] = {0.f, 0.f, 0.f, 0.f, 0.f, 0.f, 0.f, 0.f};
  const float2* base = in + (size_t)t * NPIX;
  for (int j = 0; j < NX; ++j) {
    float2 a = base[j * NY + v];
#pragma unroll
    for (int r = 0; r < 8; ++r) {
      float2 g = grow[r][j];
      float gi = sgn * g.y;
      ar[r] += a.x * g.x - a.y * gi;
      ai[r] += a.x * gi + a.y * g.x;
    }
  }
  float l1 = 0.f, l2 = 0.f;
  if (EPI >= 2) { l1 = fmaxf(l1p[0], 0.f); l2 = fmaxf(l2p[0], 0.f); }
#pragma unroll
  for (int r = 0; r < 8; ++r) {
    size_t idx = (size_t)t * NPIX + (size_t)(u0 + r) * NY + v;
    if (EPI == 0) {
      ((float2*)outv)[idx] = make_float2(ar[r], ai[r]);
    } else if (EPI == 1) {
      float m = (float)maskp[idx];
      ((float2*)outv)[idx] = make_float2(m * (m * ar[r] - dr[idx]),
                                         m * (m * ai[r] - di[idx]));
    } else if (EPI == 2) {
      float2 x = xrec2[idx], bb = beta2[idx], tt = tbuf2[idx];
      ((float*)outv)[2 * idx]     = (1.f + l2) * x.x - l1 * ar[r] + l2 * (bb.x - tt.x);
      ((float*)outv)[2 * idx + 1] = (1.f + l2) * x.y - l1 * ai[r] + l2 * (bb.y - tt.y);
    } else {
      float2 x = xrec2[idx];
      ((float*)outv)[2 * idx]     = (1.f + l2) * x.x - l1 * ar[r];
      ((float*)outv)[2 * idx + 1] = (1.f + l2) * x.y - l1 * ai[r];
    }
  }
}

// ---------------------------------------------------------------------------
// Eigen part: 2 sweeps of parallel-pairs complex Hermitian Jacobi (3-phase,
// 256 threads — the measured-best structure). MODE 1: init from Agram.
// MODE 2: continue from scratch. MODE 3: continue + threshold + W output.
// ---------------------------------------------------------------------------
template <int MODE>
__device__ void eigen_part(const float2* __restrict__ Ain, float* __restrict__ scr,
                           const float* __restrict__ tcp, float2* __restrict__ Wout) {
  __shared__ float Ar[NT][NT], Ai_[NT][NT], Vr[NT][NT], Vi_[NT][NT];
  __shared__ float cS[9], sS[9], erS[9], eiS[9];
  __shared__ int pS[9], qS[9];
  __shared__ float ratio[NT];
  int tid = threadIdx.x;
  for (int idx = tid; idx < NT * NT; idx += 256) {
    int i = idx / NT, j = idx - (idx / NT) * NT;
    if (MODE == 1) {
      float2 a = Ain[idx];
      Ar[i][j] = a.x;
      Ai_[i][j] = (i == j) ? 0.f : a.y;
      Vr[i][j] = (i == j) ? 1.f : 0.f;
      Vi_[i][j] = 0.f;
    } else {
      Ar[i][j] = scr[idx];
      Ai_[i][j] = scr[324 + idx];
      Vr[i][j] = scr[648 + idx];
      Vi_[i][j] = scr[972 + idx];
    }
  }
  __syncthreads();
  for (int sweep = 0; sweep < 2; ++sweep) {
    for (int r = 0; r < NT - 1; ++r) {
      if (tid < 9) {
        int k = tid;
        int a = (r + k) % (NT - 1);
        int b = (k == 0) ? (NT - 1) : (r - k + (NT - 1)) % (NT - 1);
        int p = min(a, b), q = max(a, b);
        pS[k] = p; qS[k] = q;
        float apr = Ar[p][q], api = Ai_[p][q];
        float r2 = apr * apr + api * api;
        float c = 1.f, s = 0.f, er = 1.f, ei = 0.f;
        if (r2 > 1e-28f) {
          float rr = sqrtf(r2);
          float inv_r = 1.f / rr;
          er = apr * inv_r; ei = api * inv_r;          // e = apq/|apq|
          float th = (Ar[q][q] - Ar[p][p]) * 0.5f * inv_r;
          float tt = (th >= 0.f ? 1.f : -1.f) / (fabsf(th) + sqrtf(th * th + 1.f));
          c = 1.f / sqrtf(tt * tt + 1.f);
          s = tt * c;
        }
        cS[k] = c; sS[k] = s; erS[k] = er; eiS[k] = ei;
      }
      __syncthreads();
      if (tid < 9 * NT) {
        int idx = tid;
        int k = idx / 9, j = idx - (idx / 9) * 9;
        int p = pS[j], q = qS[j];
        float c = cS[j], s = sS[j], er = erS[j], ei = eiS[j];
        float apr = Ar[k][p], api = Ai_[k][p];
        float aqr = Ar[k][q], aqi = Ai_[k][q];
        float eqr = er * aqr + ei * aqi;               // conj(e)*a_q
        float eqi = er * aqi - ei * aqr;
        Ar[k][p] = c * apr - s * eqr;  Ai_[k][p] = c * api - s * eqi;
        Ar[k][q] = s * apr + c * eqr;  Ai_[k][q] = s * api + c * eqi;
        float vpr = Vr[k][p], vpi = Vi_[k][p];
        float vqr = Vr[k][q], vqi = Vi_[k][q];
        float evr = er * vqr + ei * vqi;
        float evi = er * vqi - ei * vqr;
        Vr[k][p] = c * vpr - s * evr;  Vi_[k][p] = c * vpi - s * evi;
        Vr[k][q] = s * vpr + c * evr;  Vi_[k][q] = s * vpi + c * evi;
      }
      __syncthreads();
      if (tid < 9 * NT) {
        int idx = tid;
        int k = idx / 9, j = idx - (idx / 9) * 9;
        int p = pS[j], q = qS[j];
        float c = cS[j], s = sS[j], er = erS[j], ei = eiS[j];
        float bpr = Ar[p][k], bpi = Ai_[p][k];
        float bqr = Ar[q][k], bqi = Ai_[q][k];
        float ebr = er * bqr - ei * bqi;               // e*b_q
        float ebi = er * bqi + ei * bqr;
        Ar[p][k] = c * bpr - s * ebr;  Ai_[p][k] = c * bpi - s * ebi;
        Ar[q][k] = s * bpr + c * ebr;  Ai_[q][k] = s * bpi + c * ebi;
      }
      __syncthreads();
    }
  }
  if (MODE == 3) {
    if (tid == 0) {
      float smax = 0.f;
      for (int k = 0; k < NT; ++k) {
        float sv = sqrtf(fmaxf(Ar[k][k], 0.f));
        ratio[k] = sv;
        smax = fmaxf(smax, sv);
      }
      float sig = 1.f / (1.f + expf(-tcp[0]));
      float thres = sig * smax;
      for (int k = 0; k < NT; ++k) {
        float sv = ratio[k];
        ratio[k] = (sv > thres) ? (sv - thres) / sv : 0.f;
      }
    }
    __syncthreads();
    for (int idx = tid; idx < NT * NT; idx += 256) {
      int i = idx / NT, j = idx - (idx / NT) * NT;
      float wr = 0.f, wi = 0.f;
      for (int k = 0; k < NT; ++k) {
        float rk = ratio[k];
        wr += rk * (Vr[i][k] * Vr[j][k] + Vi_[i][k] * Vi_[j][k]);
        wi += rk * (Vi_[i][k] * Vr[j][k] - Vr[i][k] * Vi_[j][k]);
      }
      Wout[idx] = make_float2(wr, wi);
    }
  } else {
    for (int idx = tid; idx < NT * NT; idx += 256) {
      int i = idx / NT, j = idx - (idx / NT) * NT;
      scr[idx]       = Ar[i][j];
      scr[324 + idx] = Ai_[i][j];
      scr[648 + idx] = Vr[i][j];
      scr[972 + idx] = Vi_[i][j];
    }
  }
}

// ---------------------------------------------------------------------------
// LDS-staged MFMA conv3d 3x3x3, CIN=16 -> COUT (16 or 2), fp16 NDHWC, SAME.
// R12-proven geometry: block = (z, 4 y-rows, x-half); 20 tiles; wave<->y-row;
// LDS 18 rows x 164 chunks x 16B = 46.1 KB -> 3 blocks/CU.
// XCD-chunk block swizzle keeps each XCD on a contiguous z-slab.
// Non-soft staging: global_load_lds width=16 into exactly-linear LDS (pads
// pre-zeroed). Soft staging: register path with threshold.
// EIG>0: blockIdx 0 runs eigen_part<EIG>. outReal: fused extract_real.
// PAIRED: grid 2x1440; blocks [1440,2880) process (in1 -> out1, resSign1).
// ---------------------------------------------------------------------------
#define ROWCH 164                 // chunks per LDS row (82 voxels * 2)
#define NROWS 18                  // 3 z-planes x 6 y-rows
#define NCHUNK (NROWS*ROWCH)      // 2952
#define NBLK 1440

template <int COUT, bool RELU, int OUTMODE, bool SOFT, int EIG, bool PAIRED>
__global__ void __launch_bounds__(256)
conv3d_mfma_kernel(const __half* __restrict__ in_, const float* __restrict__ wts,
                   void* __restrict__ out_, const float* __restrict__ res, float resSign,
                   const float* __restrict__ thrp,
                   const float2* __restrict__ eigA, float* __restrict__ eigScr,
                   const float* __restrict__ tcp, float2* __restrict__ eigW,
                   float* __restrict__ outReal,
                   const __half* __restrict__ in1, void* __restrict__ out1, float resSign1) {
  if constexpr (EIG > 0) {
    if (blockIdx.x == 0) { eigen_part<EIG>(eigA, eigScr, tcp, eigW); return; }
  }
  __shared__ alignas(16) __half lds[NCHUNK * 8];   // 46.1 KB
  const int tid = threadIdx.x;
  int bid0 = (EIG > 0) ? ((int)blockIdx.x - 1) : (int)blockIdx.x;
  const __half* inp = in_;
  void* outp = out_;
  float rs = resSign;
  bool dosoft = SOFT;
  float* oreal = outReal;
  if (PAIRED && bid0 >= NBLK) {
    bid0 -= NBLK; inp = in1; outp = out1; rs = resSign1; dosoft = false; oreal = nullptr;
  }
  const int bid = (bid0 & 7) * 180 + (bid0 >> 3);  // 1440 % 8 == 0 -> bijective
  const int z   = bid / 80;                        // 18 * 40 * 2 = 1440
  const int rem = bid - z * 80;
  const int y0  = (rem >> 1) * 4;                  // 4 output rows
  const int xbase = (rem & 1) * 80;                // x-half

  const int lane = tid & 63;
  const int wv = tid >> 6;        // wave <-> y-row (yloc = wv)
  const int n = lane & 15;        // B col (co) / output voxel col
  const int g = lane >> 4;        // k-group (0..3)
  const int sel = g >> 1;         // which tap of the chunk's pair
  const int ci = (g & 1) * 8;     // ci offset within tap

  // B fragments: bw[c][j] = W[k = c*32 + g*8 + j][n], zero-padded
  half8t bw[14];
#pragma unroll
  for (int c = 0; c < 14; ++c) {
#pragma unroll
    for (int j = 0; j < 8; ++j) {
      int kg = c * 32 + g * 8 + j;
      float w = (kg < 432 && n < COUT) ? wts[kg * COUT + n] : 0.f;
      bw[c][j] = (_Float16)w;
    }
  }

  if (!dosoft) {
    half8t zero8 = {0, 0, 0, 0, 0, 0, 0, 0};
    // x-pad chunks: 2 per row (left pad for x-half 0, right pad for half 1)
    if (tid < 2 * NROWS) {
      int row = tid >> 1, which = tid & 1;
      int off = (xbase == 0) ? which : (162 + which);
      *reinterpret_cast<half8t*>(&lds[(row * ROWCH + off) * 8]) = zero8;
    }
    // OOB rows fully zeroed
#pragma unroll 1
    for (int row = 0; row < NROWS; ++row) {
      int zz = z - 1 + row / 6;
      int yy = y0 - 1 + row % 6;
      if ((unsigned)zz >= (unsigned)NT || (unsigned)yy >= (unsigned)NX) {
        for (int i = tid; i < ROWCH; i += 256)
          *reinterpret_cast<half8t*>(&lds[(row * ROWCH + i) * 8]) = zero8;
      }
    }
    // async direct-to-LDS stage (linear LDS: chunk i -> i*16B)
    const int wb = tid & ~63;
#pragma unroll 1
    for (int base = 0; base < NCHUNK; base += 256) {
      int i = base + tid;
      if (i < NCHUNK) {
        int row = i / ROWCH;
        int off = i - row * ROWCH;
        int zz = z - 1 + row / 6;
        int yy = y0 - 1 + row % 6;
        int x = xbase - 1 + (off >> 1);
        bool valid = ((unsigned)zz < (unsigned)NT) && ((unsigned)yy < (unsigned)NX) &&
                     ((unsigned)x < (unsigned)NY);
        if (valid) {
          const __half* src = inp + ((size_t)((zz * NX + yy) * NY + x)) * 16 + (off & 1) * 8;
          __builtin_amdgcn_global_load_lds(
              (gu32*)(const void*)src,
              (lu32*)(void*)&lds[(size_t)(base + wb) * 8],
              16, 0, 0);
        }
      }
    }
  } else {
    float thr = SOFT ? thrp[0] : 0.f;
    for (int i = tid; i < NCHUNK; i += 256) {
      int row = i / ROWCH;
      int off = i - row * ROWCH;
      int zz = z - 1 + row / 6;
      int yy = y0 - 1 + row % 6;
      int x = xbase - 1 + (off >> 1);
      half8t v = {0, 0, 0, 0, 0, 0, 0, 0};
      if ((unsigned)zz < (unsigned)NT && (unsigned)yy < (unsigned)NX &&
          (unsigned)x < (unsigned)NY) {
        v = *reinterpret_cast<const half8t*>(
              inp + ((size_t)((zz * NX + yy) * NY + x)) * 16 + (off & 1) * 8);
#pragma unroll
        for (int e = 0; e < 8; ++e) {
          float f = (float)v[e];
          v[e] = (_Float16)copysignf(fmaxf(fabsf(f) - thr, 0.f), f);
        }
      }
      *reinterpret_cast<half8t*>(&lds[(size_t)i * 8]) = v;
    }
  }
  __syncthreads();

  const int yloc = wv;
#pragma unroll 1
  for (int t = 0; t < 5; ++t) {
    int xloc = t * 16;

    f32x4 acc = {0.f, 0.f, 0.f, 0.f};
#pragma unroll
    for (int c = 0; c < 14; ++c) {
      const int t0 = 2 * c, t1 = 2 * c + 1;
      const int dz0 = t0 / 9, dy0 = (t0 / 3) % 3, dx0 = t0 % 3;
      const int dz1 = t1 / 9, dy1 = (t1 / 3) % 3, dx1 = t1 % 3;
      half8t a = {0, 0, 0, 0, 0, 0, 0, 0};
      if (c < 13 || !sel) {                 // tap 27 (c==13,sel) = zero pad
        int dz = sel ? dz1 : dz0;
        int dy = sel ? dy1 : dy0;
        int dx = sel ? dx1 : dx0;
        int rowi = dz * 6 + yloc + dy;      // 0..17
        int slot = xloc + n + dx;           // 0..81
        int aoff = rowi * (ROWCH * 8) + slot * 16 + ci;     // halves; 16B aligned
        a = *reinterpret_cast<const half8t*>(&lds[aoff]);
      }
      acc = __builtin_amdgcn_mfma_f32_16x16x32_f16(a, bw[c], acc, 0, 0, 0);
    }

    size_t vb = ((size_t)(z * NX) + (y0 + yloc)) * NY + xbase + xloc;
    if (n < COUT) {
#pragma unroll
      for (int r = 0; r < 4; ++r) {
        float v = acc[r];
        size_t oidx = (vb + g * 4 + r) * COUT + n;
        if (res) v += rs * res[oidx];
        if (RELU) v = fmaxf(v, 0.f);
        if (OUTMODE == 1) ((__half*)outp)[oidx] = __float2half(v);
        else {
          ((float*)outp)[oidx] = v;
          if (COUT == 2 && oreal && n == 0) oreal[vb + g * 4 + r] = v;
        }
      }
    }
  }
}

// ---------------------------------------------------------------------------
// MFMA conv3d for the 2->16 first layer: K = 54 (pad 64), 2 MFMA per tile.
// ---------------------------------------------------------------------------
template <bool RELU>
__global__ void __launch_bounds__(256)
conv3d_mfma2in_kernel(const float* __restrict__ in_, const float* __restrict__ wts,
                      __half* __restrict__ out_) {
  __shared__ alignas(8) __half lds2[12 * 324];    // 12 rows x 162 vox x 2ch
  const int tid = threadIdx.x;
  const int bid0 = (int)blockIdx.x;
  const int bid = (bid0 & 7) * 180 + (bid0 >> 3);
  const int z  = bid / 80;                        // grid = 1440
  const int y0 = (bid - z * 80) * 2;
  const int lane = tid & 63;
  const int wv = tid >> 6;
  const int n = lane & 15;
  const int g = lane >> 4;

  // B fragments: k = c*32+g*8+j; tap=k>>1, ch=k&1; wts layout [tap][ch][co]
  half8t bw[2];
#pragma unroll
  for (int c = 0; c < 2; ++c) {
#pragma unroll
    for (int j = 0; j < 8; ++j) {
      int k = c * 32 + g * 8 + j;
      float w = (k < 54) ? wts[k * 16 + n] : 0.f;
      bw[c][j] = (_Float16)w;
    }
  }

  // stage (fp32 -> fp16)
  for (int i = tid; i < 12 * 162; i += 256) {
    int row = i / 162;
    int vox = i - row * 162;
    int zz = z - 1 + (row >> 2);
    int yy = y0 - 1 + (row & 3);
    int xx = vox - 1;
    half2t v2 = {(_Float16)0.f, (_Float16)0.f};
    if ((unsigned)zz < (unsigned)NT && (unsigned)yy < (unsigned)NX && (unsigned)xx < (unsigned)NY) {
      float2 f = reinterpret_cast<const float2*>(in_)[(size_t)(zz * NX + yy) * NY + xx];
      v2[0] = (_Float16)f.x;
      v2[1] = (_Float16)f.y;
    }
    *reinterpret_cast<half2t*>(&lds2[i * 2]) = v2;
  }
  __syncthreads();

#pragma unroll 1
  for (int t = 0; t < 5; ++t) {
    int tl = wv * 5 + t;
    int yloc = (tl >= 10) ? 1 : 0;
    int x0 = (tl - yloc * 10) * 16;
    f32x4 acc = {0.f, 0.f, 0.f, 0.f};
#pragma unroll
    for (int c = 0; c < 2; ++c) {
      half8t a = {0, 0, 0, 0, 0, 0, 0, 0};
#pragma unroll
      for (int u = 0; u < 4; ++u) {
        int tap = c * 16 + g * 4 + u;
        if (tap < 27) {
          int dz = tap / 9, dy = (tap / 3) % 3, dx = tap % 3;
          int rowi = dz * 4 + yloc + dy;
          half2t p = *reinterpret_cast<const half2t*>(&lds2[rowi * 324 + (x0 + n + dx) * 2]);
          a[2 * u] = p[0];
          a[2 * u + 1] = p[1];
        }
      }
      acc = __builtin_amdgcn_mfma_f32_16x16x32_f16(a, bw[c], acc, 0, 0, 0);
    }
    size_t vb = ((size_t)(z * NX) + (y0 + yloc)) * NY + x0;
#pragma unroll
    for (int r = 0; r < 4; ++r) {
      float v = acc[r];
      if (RELU) v = fmaxf(v, 0.f);
      out_[(vb + g * 4 + r) * 16 + n] = __float2half(v);
    }
  }
}

// ---------------------------------------------------------------------------
// SVD path: Gram + svd_apply (eigen runs fused inside sym convs).
// ---------------------------------------------------------------------------
__global__ void gram_kernel(const float2* __restrict__ M, float2* __restrict__ A) {
  int b = blockIdx.x;  // 0..170 upper-triangular pair
  int i = 0;
  while (b >= NT - i) { b -= NT - i; ++i; }
  int j = i + b;
  int tid = threadIdx.x;
  float sr = 0.f, si = 0.f;
  for (int p = tid; p < NPIX; p += 256) {
    float2 a = M[(size_t)i * NPIX + p];
    float2 c = M[(size_t)j * NPIX + p];
    sr += a.x * c.x + a.y * c.y;   // a * conj(c)
    si += a.y * c.x - a.x * c.y;
  }
  __shared__ float rs[256], is_[256];
  rs[tid] = sr; is_[tid] = si;
  __syncthreads();
  for (int s = 128; s > 0; s >>= 1) {
    if (tid < s) { rs[tid] += rs[tid + s]; is_[tid] += is_[tid + s]; }
    __syncthreads();
  }
  if (tid == 0) {
    A[i * NT + j] = make_float2(rs[0], is_[0]);
    if (i != j) A[j * NT + i] = make_float2(rs[0], -is_[0]);
  }
}

// t = W M;  beta (+)= eta*(M - t).  FIRST: beta is logically zero -> write.
template <bool FIRST>
__global__ void svd_apply_kernel(const float2* __restrict__ M, const float2* __restrict__ Wm,
                                 float2* __restrict__ t, float2* __restrict__ beta,
                                 const float* __restrict__ etap) {
  __shared__ float2 W[NT * NT];
  int tid = threadIdx.x;
  for (int i = tid; i < NT * NT; i += 256) W[i] = Wm[i];
  __syncthreads();
  int p = blockIdx.x * 256 + tid;  // exact: 100*256 == NPIX
  float eta = fmaxf(etap[0], 0.f);
  float2 m[NT];
#pragma unroll
  for (int j = 0; j < NT; ++j) m[j] = M[(size_t)j * NPIX + p];
#pragma unroll
  for (int i = 0; i < NT; ++i) {
    float tr = 0.f, ti = 0.f;
#pragma unroll
    for (int j = 0; j < NT; ++j) {
      float2 w = W[i * NT + j];
      tr += w.x * m[j].x - w.y * m[j].y;
      ti += w.x * m[j].y + w.y * m[j].x;
    }
    t[(size_t)i * NPIX + p] = make_float2(tr, ti);
    if (FIRST) {
      beta[(size_t)i * NPIX + p] = make_float2(eta * (m[i].x - tr), eta * (m[i].y - ti));
    } else {
      float2 b = beta[(size_t)i * NPIX + p];
      b.x += eta * (m[i].x - tr);
      b.y += eta * (m[i].y - ti);
      beta[(size_t)i * NPIX + p] = b;
    }
  }
}

// ---------------------------------------------------------------------------
extern "C" void kernel_launch(void* const* d_in, const int* in_sizes, int n_in,
                              void* d_out, int out_size, void* d_ws, size_t ws_size,
                              hipStream_t stream) {
  // Inputs fp32; mask int32. Output fp32, layout:
  //   out[0 : 460800]                  = real(x_rec)
  //   out[460800 + 921600*i : +921600] = X_SYM[i]
  const float* d_real    = (const float*)d_in[0];
  const float* d_imag    = (const float*)d_in[1];
  const int*   mask      = (const int*)d_in[2];
  const float* W1        = (const float*)d_in[3];
  const float* W2        = (const float*)d_in[4];
  const float* W3        = (const float*)d_in[5];
  const float* W4        = (const float*)d_in[6];
  const float* W5        = (const float*)d_in[7];
  const float* W6        = (const float*)d_in[8];
  const float* lam1      = (const float*)d_in[9];
  const float* lam2      = (const float*)d_in[10];
  const float* soft_thr  = (const float*)d_in[11];
  const float* thres_c   = (const float*)d_in[12];
  const float* eta       = (const float*)d_in[13];
  float* out = (float*)d_out;
  (void)in_sizes; (void)n_in;

  const size_t NEEDED = 74200000ull;
  if (ws_size < NEEDED) {
    probe_kernel<<<(out_size + 255) / 256, 256, 0, stream>>>(out, out_size,
                                                             (float)(ws_size >> 20));
    return;
  }

  char* wp_ = (char*)d_ws;
  auto alloc = [&](size_t bytes) {
    char* r = wp_;
    wp_ += (bytes + 255) & ~(size_t)255;
    return r;
  };
  float2* G      = (float2*)alloc((size_t)NPIX * sizeof(float2));
  float2* xrec   = (float2*)alloc((size_t)NVOX * sizeof(float2));
  float2* tbuf   = (float2*)alloc((size_t)NVOX * sizeof(float2));
  float2* beta   = (float2*)alloc((size_t)NVOX * sizeof(float2));
  float*  Rf     = (float*)alloc((size_t)NVOX * 2 * sizeof(float));
  __half* Af     = (__half*)alloc((size_t)NVOX * 16 * sizeof(__half));
  __half* Bf     = (__half*)alloc((size_t)NVOX * 16 * sizeof(__half));
  __half* Cf     = (__half*)alloc((size_t)NVOX * 16 * sizeof(__half));
  __half* Df     = (__half*)alloc((size_t)NVOX * 16 * sizeof(__half));
  float2* Agram  = (float2*)alloc((size_t)NT * NT * sizeof(float2));
  float2* Wmat   = (float2*)alloc((size_t)NT * NT * sizeof(float2));
  float*  EigScr = (float*)alloc(1296 * sizeof(float));
  float2* T1 = (float2*)Af;
  float2* T2 = (float2*)Bf;

  make_g_kernel<<<100, 256, 0, stream>>>(G);

  // x_rec = ifft2c(mask * d)   (mask_d fused into the first FFT pass)
  fft_pass_last8<1><<<360, 160, 0, stream>>>(nullptr, T2, G, 1, d_real, d_imag, mask);
  fft_pass_mid8<0><<<360, 160, 0, stream>>>(T2, xrec, G, 1, nullptr, nullptr, nullptr,
                                            nullptr, nullptr, nullptr, nullptr, nullptr);

  for (int i = 0; i < 3; ++i) {
    // fft2c(x_rec), fused mask_q; then ifft2c, fused rn -> Rf
    fft_pass_last8<0><<<360, 160, 0, stream>>>(xrec, T1, G, 0, nullptr, nullptr, nullptr);
    fft_pass_mid8<1><<<360, 160, 0, stream>>>(T1, T2, G, 0, d_real, d_imag, mask,
                                              nullptr, nullptr, nullptr, nullptr, nullptr);
    fft_pass_last8<0><<<360, 160, 0, stream>>>(T2, T1, G, 1, nullptr, nullptr, nullptr);
    if (i == 0) {
      fft_pass_mid8<3><<<360, 160, 0, stream>>>(T1, Rf, G, 1, nullptr, nullptr, nullptr,
                                                xrec, nullptr, nullptr, lam1 + i, lam2 + i);
    } else {
      fft_pass_mid8<2><<<360, 160, 0, stream>>>(T1, Rf, G, 1, nullptr, nullptr, nullptr,
                                                xrec, beta, tbuf, lam1 + i, lam2 + i);
    }
    // main conv chain (MFMA throughout)
    conv3d_mfma2in_kernel<true><<<1440, 256, 0, stream>>>(Rf, W1 + (size_t)i * 864, Af);
    conv3d_mfma_kernel<16, true, 1, false, 0, false><<<1440, 256, 0, stream>>>(
        Af, W2 + (size_t)i * 6912, Bf, nullptr, 0.f, nullptr,
        nullptr, nullptr, nullptr, nullptr, nullptr, nullptr, nullptr, 0.f);
    conv3d_mfma_kernel<16, false, 1, false, 0, false><<<1440, 256, 0, stream>>>(
        Bf, W3 + (size_t)i * 6912, Cf, nullptr, 0.f, nullptr,
        nullptr, nullptr, nullptr, nullptr, nullptr, nullptr, nullptr, 0.f);

    if (i < 2) {
      // W4 on soft(x3) (threshold fused into staging); W5; W6 -> xrec
      conv3d_mfma_kernel<16, true, 1, true, 0, false><<<1440, 256, 0, stream>>>(
          Cf, W4 + (size_t)i * 6912, Bf, nullptr, 0.f, soft_thr + i,
          nullptr, nullptr, nullptr, nullptr, nullptr, nullptr, nullptr, 0.f);
      conv3d_mfma_kernel<16, true, 1, false, 0, false><<<1440, 256, 0, stream>>>(
          Bf, W5 + (size_t)i * 6912, Af, nullptr, 0.f, nullptr,
          nullptr, nullptr, nullptr, nullptr, nullptr, nullptr, nullptr, 0.f);
      conv3d_mfma_kernel<2, false, 0, false, 0, false><<<1440, 256, 0, stream>>>(
          Af, W6 + (size_t)i * 864, (float*)xrec, Rf, 1.f, nullptr,
          nullptr, nullptr, nullptr, nullptr, nullptr, nullptr, nullptr, 0.f);
      gram_kernel<<<171, 256, 0, stream>>>((const float2*)xrec, Agram);
      // sym branch with the 1-block Jacobi hidden inside (2 sweeps per part)
      conv3d_mfma_kernel<16, true, 1, false, 1, false><<<1441, 256, 0, stream>>>(
          Cf, W4 + (size_t)i * 6912, Bf, nullptr, 0.f, nullptr,
          Agram, EigScr, thres_c + i, Wmat, nullptr, nullptr, nullptr, 0.f);
      conv3d_mfma_kernel<16, true, 1, false, 2, false><<<1441, 256, 0, stream>>>(
          Bf, W5 + (size_t)i * 6912, Af, nullptr, 0.f, nullptr,
          Agram, EigScr, thres_c + i, Wmat, nullptr, nullptr, nullptr, 0.f);
      conv3d_mfma_kernel<2, false, 0, false, 3, false><<<1441, 256, 0, stream>>>(
          Af, W6 + (size_t)i * 864, out + 460800 + (size_t)921600 * i, Rf, -1.f, nullptr,
          Agram, EigScr, thres_c + i, Wmat, nullptr, nullptr, nullptr, 0.f);
      if (i == 0)
        svd_apply_kernel<true><<<100, 256, 0, stream>>>((const float2*)xrec, Wmat, tbuf, beta, eta + i);
      else
        svd_apply_kernel<false><<<100, 256, 0, stream>>>((const float2*)xrec, Wmat, tbuf, beta, eta + i);
    } else {
      // final iteration: no low-rank step -> main and sym chains are fully
      // independent given Cf/Rf; pair them into 3 double-grid dispatches.
      conv3d_mfma_kernel<16, true, 1, true, 0, true><<<2880, 256, 0, stream>>>(
          Cf, W4 + (size_t)i * 6912, Bf, nullptr, 0.f, soft_thr + i,
          nullptr, nullptr, nullptr, nullptr, nullptr, Cf, Df, 0.f);
      conv3d_mfma_kernel<16, true, 1, false, 0, true><<<2880, 256, 0, stream>>>(
          Bf, W5 + (size_t)i * 6912, Af, nullptr, 0.f, nullptr,
          nullptr, nullptr, nullptr, nullptr, nullptr, Df, Cf, 0.f);
      conv3d_mfma_kernel<2, false, 0, false, 0, true><<<2880, 256, 0, stream>>>(
          Af, W6 + (size_t)i * 864, (float*)xrec, Rf, 1.f, nullptr,
          nullptr, nullptr, nullptr, nullptr, out,
          Cf, out + 460800 + (size_t)921600 * i, -1.f);
    }
  }
}

// Round 16
// 1195.136 us; speedup vs baseline: 1.1367x; 1.1367x over previous
//
#include <hip/hip_runtime.h>
#include <hip/hip_fp16.h>

#define NT 18
#define NX 160
#define NY 160
#define NPIX (NX*NY)      // 25600
#define NVOX (NT*NPIX)    // 460800

typedef _Float16 __attribute__((ext_vector_type(2))) half2t;
typedef _Float16 __attribute__((ext_vector_type(8))) half8t;
typedef float    __attribute__((ext_vector_type(4))) f32x4;
typedef unsigned int u32;
typedef __attribute__((address_space(1))) const u32 gu32;
typedef __attribute__((address_space(3))) u32 lu32;

// ---------------------------------------------------------------------------
__global__ void probe_kernel(float* __restrict__ out, int n, float val) {
  int i = blockIdx.x * 256 + threadIdx.x;
  if (i < n) out[i] = val;
}

// ---------------------------------------------------------------------------
// DFT matrix G[u][j] = F[(u+80)%160][(j+80)%160], F = ortho DFT(160).
// fft2c(X) = G X G (G symmetric); ifft2c(X) = conj(G) X conj(G).
// ---------------------------------------------------------------------------
__global__ void make_g_kernel(float2* __restrict__ G) {
  int idx = blockIdx.x * 256 + threadIdx.x;
  if (idx >= NPIX) return;
  int r = idx / NY, c = idx - (idx / NY) * NY;
  int rs = (r + 80) % 160;
  int cs = (c + 80) % 160;
  int prod = (rs * cs) % 160;
  double ang = -2.0 * 3.14159265358979323846 * (double)prod / 160.0;
  double sc = 0.07905694150420949;  // 1/sqrt(160)
  G[idx] = make_float2((float)(cos(ang) * sc), (float)(sin(ang) * sc));
}

// ---------------------------------------------------------------------------
// FFT pass over last axis, 4 rows per block (720 blocks — measured-best).
// MASKD=1: rows are loaded as mask*d (fuses the former mask_d kernel).
// ---------------------------------------------------------------------------
template <int MASKD>
__global__ void fft_pass_last4(const float2* __restrict__ in, float2* __restrict__ out,
                               const float2* __restrict__ G, int conjf,
                               const float* __restrict__ dr, const float* __restrict__ di,
                               const int* __restrict__ maskp) {
  __shared__ float2 rows[4][NY];
  int r0 = blockIdx.x * 4;      // 720 blocks * 4 = NT*NX rows
  int v = threadIdx.x;          // 0..159
#pragma unroll
  for (int r = 0; r < 4; ++r) {
    size_t idx = (size_t)(r0 + r) * NY + v;
    if (MASKD) {
      float m = (float)maskp[idx];
      rows[r][v] = make_float2(m * dr[idx], m * di[idx]);
    } else {
      rows[r][v] = in[idx];
    }
  }
  __syncthreads();
  float sgn = conjf ? -1.f : 1.f;
  float ar[4] = {0.f, 0.f, 0.f, 0.f}, ai[4] = {0.f, 0.f, 0.f, 0.f};
  for (int k = 0; k < NY; ++k) {
    float2 g = G[k * NY + v];
    float gi = sgn * g.y;
#pragma unroll
    for (int r = 0; r < 4; ++r) {
      float2 a = rows[r][k];
      ar[r] += a.x * g.x - a.y * gi;
      ai[r] += a.x * gi + a.y * g.x;
    }
  }
#pragma unroll
  for (int r = 0; r < 4; ++r)
    out[(size_t)(r0 + r) * NY + v] = make_float2(ar[r], ai[r]);
}

// ---------------------------------------------------------------------------
// FFT pass over middle axis, 4 u-values per block (720 blocks, XCD-swizzled).
// EPI=0: plain write.  EPI=1: fused mask_q.  EPI=2: fused rn -> Rf.
// EPI=3: fused rn, iteration 0 (beta = t = 0; no loads) — exact.
// ---------------------------------------------------------------------------
template <int EPI>
__global__ void fft_pass_mid4(const float2* __restrict__ in, void* __restrict__ outv,
                              const float2* __restrict__ G, int conjf,
                              const float* __restrict__ dr, const float* __restrict__ di,
                              const int* __restrict__ maskp,
                              const float2* __restrict__ xrec2, const float2* __restrict__ beta2,
                              const float2* __restrict__ tbuf2,
                              const float* __restrict__ l1p, const float* __restrict__ l2p) {
  __shared__ float2 grow[4][NX];
  int b = (int)blockIdx.x;
  int sb = (b & 7) * 90 + (b >> 3);     // 720 % 8 == 0 -> bijective
  int t = sb / 40;                      // 18 * 40 = 720 blocks
  int u0 = (sb - t * 40) * 4;
  int v = threadIdx.x;
#pragma unroll
  for (int r = 0; r < 4; ++r) grow[r][v] = G[(u0 + r) * NX + v];
  __syncthreads();
  float sgn = conjf ? -1.f : 1.f;
  float ar[4] = {0.f, 0.f, 0.f, 0.f}, ai[4] = {0.f, 0.f, 0.f, 0.f};
  const float2* base = in + (size_t)t * NPIX;
  for (int j = 0; j < NX; ++j) {
    float2 a = base[j * NY + v];
#pragma unroll
    for (int r = 0; r < 4; ++r) {
      float2 g = grow[r][j];
      float gi = sgn * g.y;
      ar[r] += a.x * g.x - a.y * gi;
      ai[r] += a.x * gi + a.y * g.x;
    }
  }
  float l1 = 0.f, l2 = 0.f;
  if (EPI >= 2) { l1 = fmaxf(l1p[0], 0.f); l2 = fmaxf(l2p[0], 0.f); }
#pragma unroll
  for (int r = 0; r < 4; ++r) {
    size_t idx = (size_t)t * NPIX + (size_t)(u0 + r) * NY + v;
    if (EPI == 0) {
      ((float2*)outv)[idx] = make_float2(ar[r], ai[r]);
    } else if (EPI == 1) {
      float m = (float)maskp[idx];
      ((float2*)outv)[idx] = make_float2(m * (m * ar[r] - dr[idx]),
                                         m * (m * ai[r] - di[idx]));
    } else if (EPI == 2) {
      float2 x = xrec2[idx], bb = beta2[idx], tt = tbuf2[idx];
      ((float*)outv)[2 * idx]     = (1.f + l2) * x.x - l1 * ar[r] + l2 * (bb.x - tt.x);
      ((float*)outv)[2 * idx + 1] = (1.f + l2) * x.y - l1 * ai[r] + l2 * (bb.y - tt.y);
    } else {
      float2 x = xrec2[idx];
      ((float*)outv)[2 * idx]     = (1.f + l2) * x.x - l1 * ar[r];
      ((float*)outv)[2 * idx + 1] = (1.f + l2) * x.y - l1 * ai[r];
    }
  }
}

// ---------------------------------------------------------------------------
// Eigen part: 2 sweeps of parallel-pairs complex Hermitian Jacobi (3-phase,
// 256 threads — the measured-best structure). MODE 1: init from Agram.
// MODE 2: continue from scratch. MODE 3: continue + threshold + W output.
// ---------------------------------------------------------------------------
template <int MODE>
__device__ void eigen_part(const float2* __restrict__ Ain, float* __restrict__ scr,
                           const float* __restrict__ tcp, float2* __restrict__ Wout) {
  __shared__ float Ar[NT][NT], Ai_[NT][NT], Vr[NT][NT], Vi_[NT][NT];
  __shared__ float cS[9], sS[9], erS[9], eiS[9];
  __shared__ int pS[9], qS[9];
  __shared__ float ratio[NT];
  int tid = threadIdx.x;
  for (int idx = tid; idx < NT * NT; idx += 256) {
    int i = idx / NT, j = idx - (idx / NT) * NT;
    if (MODE == 1) {
      float2 a = Ain[idx];
      Ar[i][j] = a.x;
      Ai_[i][j] = (i == j) ? 0.f : a.y;
      Vr[i][j] = (i == j) ? 1.f : 0.f;
      Vi_[i][j] = 0.f;
    } else {
      Ar[i][j] = scr[idx];
      Ai_[i][j] = scr[324 + idx];
      Vr[i][j] = scr[648 + idx];
      Vi_[i][j] = scr[972 + idx];
    }
  }
  __syncthreads();
  for (int sweep = 0; sweep < 2; ++sweep) {
    for (int r = 0; r < NT - 1; ++r) {
      if (tid < 9) {
        int k = tid;
        int a = (r + k) % (NT - 1);
        int b = (k == 0) ? (NT - 1) : (r - k + (NT - 1)) % (NT - 1);
        int p = min(a, b), q = max(a, b);
        pS[k] = p; qS[k] = q;
        float apr = Ar[p][q], api = Ai_[p][q];
        float r2 = apr * apr + api * api;
        float c = 1.f, s = 0.f, er = 1.f, ei = 0.f;
        if (r2 > 1e-28f) {
          float rr = sqrtf(r2);
          float inv_r = 1.f / rr;
          er = apr * inv_r; ei = api * inv_r;          // e = apq/|apq|
          float th = (Ar[q][q] - Ar[p][p]) * 0.5f * inv_r;
          float tt = (th >= 0.f ? 1.f : -1.f) / (fabsf(th) + sqrtf(th * th + 1.f));
          c = 1.f / sqrtf(tt * tt + 1.f);
          s = tt * c;
        }
        cS[k] = c; sS[k] = s; erS[k] = er; eiS[k] = ei;
      }
      __syncthreads();
      if (tid < 9 * NT) {
        int idx = tid;
        int k = idx / 9, j = idx - (idx / 9) * 9;
        int p = pS[j], q = qS[j];
        float c = cS[j], s = sS[j], er = erS[j], ei = eiS[j];
        float apr = Ar[k][p], api = Ai_[k][p];
        float aqr = Ar[k][q], aqi = Ai_[k][q];
        float eqr = er * aqr + ei * aqi;               // conj(e)*a_q
        float eqi = er * aqi - ei * aqr;
        Ar[k][p] = c * apr - s * eqr;  Ai_[k][p] = c * api - s * eqi;
        Ar[k][q] = s * apr + c * eqr;  Ai_[k][q] = s * api + c * eqi;
        float vpr = Vr[k][p], vpi = Vi_[k][p];
        float vqr = Vr[k][q], vqi = Vi_[k][q];
        float evr = er * vqr + ei * vqi;
        float evi = er * vqi - ei * vqr;
        Vr[k][p] = c * vpr - s * evr;  Vi_[k][p] = c * vpi - s * evi;
        Vr[k][q] = s * vpr + c * evr;  Vi_[k][q] = s * vpi + c * evi;
      }
      __syncthreads();
      if (tid < 9 * NT) {
        int idx = tid;
        int k = idx / 9, j = idx - (idx / 9) * 9;
        int p = pS[j], q = qS[j];
        float c = cS[j], s = sS[j], er = erS[j], ei = eiS[j];
        float bpr = Ar[p][k], bpi = Ai_[p][k];
        float bqr = Ar[q][k], bqi = Ai_[q][k];
        float ebr = er * bqr - ei * bqi;               // e*b_q
        float ebi = er * bqi + ei * bqr;
        Ar[p][k] = c * bpr - s * ebr;  Ai_[p][k] = c * bpi - s * ebi;
        Ar[q][k] = s * bpr + c * ebr;  Ai_[q][k] = s * bpi + c * ebi;
      }
      __syncthreads();
    }
  }
  if (MODE == 3) {
    if (tid == 0) {
      float smax = 0.f;
      for (int k = 0; k < NT; ++k) {
        float sv = sqrtf(fmaxf(Ar[k][k], 0.f));
        ratio[k] = sv;
        smax = fmaxf(smax, sv);
      }
      float sig = 1.f / (1.f + expf(-tcp[0]));
      float thres = sig * smax;
      for (int k = 0; k < NT; ++k) {
        float sv = ratio[k];
        ratio[k] = (sv > thres) ? (sv - thres) / sv : 0.f;
      }
    }
    __syncthreads();
    for (int idx = tid; idx < NT * NT; idx += 256) {
      int i = idx / NT, j = idx - (idx / NT) * NT;
      float wr = 0.f, wi = 0.f;
      for (int k = 0; k < NT; ++k) {
        float rk = ratio[k];
        wr += rk * (Vr[i][k] * Vr[j][k] + Vi_[i][k] * Vi_[j][k]);
        wi += rk * (Vi_[i][k] * Vr[j][k] - Vr[i][k] * Vi_[j][k]);
      }
      Wout[idx] = make_float2(wr, wi);
    }
  } else {
    for (int idx = tid; idx < NT * NT; idx += 256) {
      int i = idx / NT, j = idx - (idx / NT) * NT;
      scr[idx]       = Ar[i][j];
      scr[324 + idx] = Ai_[i][j];
      scr[648 + idx] = Vr[i][j];
      scr[972 + idx] = Vi_[i][j];
    }
  }
}

// ---------------------------------------------------------------------------
// LDS-staged MFMA conv3d 3x3x3, CIN=16 -> COUT (16 or 2), fp16 NDHWC, SAME.
// R12-proven geometry: block = (z, 4 y-rows, x-half); 20 tiles; wave<->y-row;
// LDS 18 rows x 164 chunks x 16B = 46.1 KB -> 3 blocks/CU.
// XCD-chunk block swizzle keeps each XCD on a contiguous z-slab.
// Non-soft staging: global_load_lds width=16 into exactly-linear LDS (pads
// pre-zeroed). Soft staging: register path with threshold.
// EIG>0: blockIdx 0 runs eigen_part<EIG>. outReal: fused extract_real.
// PAIRED: grid 2x1440; blocks [1440,2880) process (in1 -> out1, resSign1).
// ---------------------------------------------------------------------------
#define ROWCH 164                 // chunks per LDS row (82 voxels * 2)
#define NROWS 18                  // 3 z-planes x 6 y-rows
#define NCHUNK (NROWS*ROWCH)      // 2952
#define NBLK 1440

template <int COUT, bool RELU, int OUTMODE, bool SOFT, int EIG, bool PAIRED>
__global__ void __launch_bounds__(256)
conv3d_mfma_kernel(const __half* __restrict__ in_, const float* __restrict__ wts,
                   void* __restrict__ out_, const float* __restrict__ res, float resSign,
                   const float* __restrict__ thrp,
                   const float2* __restrict__ eigA, float* __restrict__ eigScr,
                   const float* __restrict__ tcp, float2* __restrict__ eigW,
                   float* __restrict__ outReal,
                   const __half* __restrict__ in1, void* __restrict__ out1, float resSign1) {
  if constexpr (EIG > 0) {
    if (blockIdx.x == 0) { eigen_part<EIG>(eigA, eigScr, tcp, eigW); return; }
  }
  __shared__ alignas(16) __half lds[NCHUNK * 8];   // 46.1 KB
  const int tid = threadIdx.x;
  int bid0 = (EIG > 0) ? ((int)blockIdx.x - 1) : (int)blockIdx.x;
  const __half* inp = in_;
  void* outp = out_;
  float rs = resSign;
  bool dosoft = SOFT;
  float* oreal = outReal;
  if (PAIRED && bid0 >= NBLK) {
    bid0 -= NBLK; inp = in1; outp = out1; rs = resSign1; dosoft = false; oreal = nullptr;
  }
  const int bid = (bid0 & 7) * 180 + (bid0 >> 3);  // 1440 % 8 == 0 -> bijective
  const int z   = bid / 80;                        // 18 * 40 * 2 = 1440
  const int rem = bid - z * 80;
  const int y0  = (rem >> 1) * 4;                  // 4 output rows
  const int xbase = (rem & 1) * 80;                // x-half

  const int lane = tid & 63;
  const int wv = tid >> 6;        // wave <-> y-row (yloc = wv)
  const int n = lane & 15;        // B col (co) / output voxel col
  const int g = lane >> 4;        // k-group (0..3)
  const int sel = g >> 1;         // which tap of the chunk's pair
  const int ci = (g & 1) * 8;     // ci offset within tap

  // B fragments: bw[c][j] = W[k = c*32 + g*8 + j][n], zero-padded
  half8t bw[14];
#pragma unroll
  for (int c = 0; c < 14; ++c) {
#pragma unroll
    for (int j = 0; j < 8; ++j) {
      int kg = c * 32 + g * 8 + j;
      float w = (kg < 432 && n < COUT) ? wts[kg * COUT + n] : 0.f;
      bw[c][j] = (_Float16)w;
    }
  }

  if (!dosoft) {
    half8t zero8 = {0, 0, 0, 0, 0, 0, 0, 0};
    // x-pad chunks: 2 per row (left pad for x-half 0, right pad for half 1)
    if (tid < 2 * NROWS) {
      int row = tid >> 1, which = tid & 1;
      int off = (xbase == 0) ? which : (162 + which);
      *reinterpret_cast<half8t*>(&lds[(row * ROWCH + off) * 8]) = zero8;
    }
    // OOB rows fully zeroed
#pragma unroll 1
    for (int row = 0; row < NROWS; ++row) {
      int zz = z - 1 + row / 6;
      int yy = y0 - 1 + row % 6;
      if ((unsigned)zz >= (unsigned)NT || (unsigned)yy >= (unsigned)NX) {
        for (int i = tid; i < ROWCH; i += 256)
          *reinterpret_cast<half8t*>(&lds[(row * ROWCH + i) * 8]) = zero8;
      }
    }
    // async direct-to-LDS stage (linear LDS: chunk i -> i*16B)
    const int wb = tid & ~63;
#pragma unroll 1
    for (int base = 0; base < NCHUNK; base += 256) {
      int i = base + tid;
      if (i < NCHUNK) {
        int row = i / ROWCH;
        int off = i - row * ROWCH;
        int zz = z - 1 + row / 6;
        int yy = y0 - 1 + row % 6;
        int x = xbase - 1 + (off >> 1);
        bool valid = ((unsigned)zz < (unsigned)NT) && ((unsigned)yy < (unsigned)NX) &&
                     ((unsigned)x < (unsigned)NY);
        if (valid) {
          const __half* src = inp + ((size_t)((zz * NX + yy) * NY + x)) * 16 + (off & 1) * 8;
          __builtin_amdgcn_global_load_lds(
              (gu32*)(const void*)src,
              (lu32*)(void*)&lds[(size_t)(base + wb) * 8],
              16, 0, 0);
        }
      }
    }
  } else {
    float thr = SOFT ? thrp[0] : 0.f;
    for (int i = tid; i < NCHUNK; i += 256) {
      int row = i / ROWCH;
      int off = i - row * ROWCH;
      int zz = z - 1 + row / 6;
      int yy = y0 - 1 + row % 6;
      int x = xbase - 1 + (off >> 1);
      half8t v = {0, 0, 0, 0, 0, 0, 0, 0};
      if ((unsigned)zz < (unsigned)NT && (unsigned)yy < (unsigned)NX &&
          (unsigned)x < (unsigned)NY) {
        v = *reinterpret_cast<const half8t*>(
              inp + ((size_t)((zz * NX + yy) * NY + x)) * 16 + (off & 1) * 8);
#pragma unroll
        for (int e = 0; e < 8; ++e) {
          float f = (float)v[e];
          v[e] = (_Float16)copysignf(fmaxf(fabsf(f) - thr, 0.f), f);
        }
      }
      *reinterpret_cast<half8t*>(&lds[(size_t)i * 8]) = v;
    }
  }
  __syncthreads();

  const int yloc = wv;
#pragma unroll 1
  for (int t = 0; t < 5; ++t) {
    int xloc = t * 16;

    f32x4 acc = {0.f, 0.f, 0.f, 0.f};
#pragma unroll
    for (int c = 0; c < 14; ++c) {
      const int t0 = 2 * c, t1 = 2 * c + 1;
      const int dz0 = t0 / 9, dy0 = (t0 / 3) % 3, dx0 = t0 % 3;
      const int dz1 = t1 / 9, dy1 = (t1 / 3) % 3, dx1 = t1 % 3;
      half8t a = {0, 0, 0, 0, 0, 0, 0, 0};
      if (c < 13 || !sel) {                 // tap 27 (c==13,sel) = zero pad
        int dz = sel ? dz1 : dz0;
        int dy = sel ? dy1 : dy0;
        int dx = sel ? dx1 : dx0;
        int rowi = dz * 6 + yloc + dy;      // 0..17
        int slot = xloc + n + dx;           // 0..81
        int aoff = rowi * (ROWCH * 8) + slot * 16 + ci;     // halves; 16B aligned
        a = *reinterpret_cast<const half8t*>(&lds[aoff]);
      }
      acc = __builtin_amdgcn_mfma_f32_16x16x32_f16(a, bw[c], acc, 0, 0, 0);
    }

    size_t vb = ((size_t)(z * NX) + (y0 + yloc)) * NY + xbase + xloc;
    if (n < COUT) {
#pragma unroll
      for (int r = 0; r < 4; ++r) {
        float v = acc[r];
        size_t oidx = (vb + g * 4 + r) * COUT + n;
        if (res) v += rs * res[oidx];
        if (RELU) v = fmaxf(v, 0.f);
        if (OUTMODE == 1) ((__half*)outp)[oidx] = __float2half(v);
        else {
          ((float*)outp)[oidx] = v;
          if (COUT == 2 && oreal && n == 0) oreal[vb + g * 4 + r] = v;
        }
      }
    }
  }
}

// ---------------------------------------------------------------------------
// MFMA conv3d for the 2->16 first layer: K = 54 (pad 64), 2 MFMA per tile.
// ---------------------------------------------------------------------------
template <bool RELU>
__global__ void __launch_bounds__(256)
conv3d_mfma2in_kernel(const float* __restrict__ in_, const float* __restrict__ wts,
                      __half* __restrict__ out_) {
  __shared__ alignas(8) __half lds2[12 * 324];    // 12 rows x 162 vox x 2ch
  const int tid = threadIdx.x;
  const int bid0 = (int)blockIdx.x;
  const int bid = (bid0 & 7) * 180 + (bid0 >> 3);
  const int z  = bid / 80;                        // grid = 1440
  const int y0 = (bid - z * 80) * 2;
  const int lane = tid & 63;
  const int wv = tid >> 6;
  const int n = lane & 15;
  const int g = lane >> 4;

  // B fragments: k = c*32+g*8+j; tap=k>>1, ch=k&1; wts layout [tap][ch][co]
  half8t bw[2];
#pragma unroll
  for (int c = 0; c < 2; ++c) {
#pragma unroll
    for (int j = 0; j < 8; ++j) {
      int k = c * 32 + g * 8 + j;
      float w = (k < 54) ? wts[k * 16 + n] : 0.f;
      bw[c][j] = (_Float16)w;
    }
  }

  // stage (fp32 -> fp16)
  for (int i = tid; i < 12 * 162; i += 256) {
    int row = i / 162;
    int vox = i - row * 162;
    int zz = z - 1 + (row >> 2);
    int yy = y0 - 1 + (row & 3);
    int xx = vox - 1;
    half2t v2 = {(_Float16)0.f, (_Float16)0.f};
    if ((unsigned)zz < (unsigned)NT && (unsigned)yy < (unsigned)NX && (unsigned)xx < (unsigned)NY) {
      float2 f = reinterpret_cast<const float2*>(in_)[(size_t)(zz * NX + yy) * NY + xx];
      v2[0] = (_Float16)f.x;
      v2[1] = (_Float16)f.y;
    }
    *reinterpret_cast<half2t*>(&lds2[i * 2]) = v2;
  }
  __syncthreads();

#pragma unroll 1
  for (int t = 0; t < 5; ++t) {
    int tl = wv * 5 + t;
    int yloc = (tl >= 10) ? 1 : 0;
    int x0 = (tl - yloc * 10) * 16;
    f32x4 acc = {0.f, 0.f, 0.f, 0.f};
#pragma unroll
    for (int c = 0; c < 2; ++c) {
      half8t a = {0, 0, 0, 0, 0, 0, 0, 0};
#pragma unroll
      for (int u = 0; u < 4; ++u) {
        int tap = c * 16 + g * 4 + u;
        if (tap < 27) {
          int dz = tap / 9, dy = (tap / 3) % 3, dx = tap % 3;
          int rowi = dz * 4 + yloc + dy;
          half2t p = *reinterpret_cast<const half2t*>(&lds2[rowi * 324 + (x0 + n + dx) * 2]);
          a[2 * u] = p[0];
          a[2 * u + 1] = p[1];
        }
      }
      acc = __builtin_amdgcn_mfma_f32_16x16x32_f16(a, bw[c], acc, 0, 0, 0);
    }
    size_t vb = ((size_t)(z * NX) + (y0 + yloc)) * NY + x0;
#pragma unroll
    for (int r = 0; r < 4; ++r) {
      float v = acc[r];
      if (RELU) v = fmaxf(v, 0.f);
      out_[(vb + g * 4 + r) * 16 + n] = __float2half(v);
    }
  }
}

// ---------------------------------------------------------------------------
// SVD path: Gram + svd_apply (eigen runs fused inside sym convs).
// ---------------------------------------------------------------------------
__global__ void gram_kernel(const float2* __restrict__ M, float2* __restrict__ A) {
  int b = blockIdx.x;  // 0..170 upper-triangular pair
  int i = 0;
  while (b >= NT - i) { b -= NT - i; ++i; }
  int j = i + b;
  int tid = threadIdx.x;
  float sr = 0.f, si = 0.f;
  for (int p = tid; p < NPIX; p += 256) {
    float2 a = M[(size_t)i * NPIX + p];
    float2 c = M[(size_t)j * NPIX + p];
    sr += a.x * c.x + a.y * c.y;   // a * conj(c)
    si += a.y * c.x - a.x * c.y;
  }
  __shared__ float rs[256], is_[256];
  rs[tid] = sr; is_[tid] = si;
  __syncthreads();
  for (int s = 128; s > 0; s >>= 1) {
    if (tid < s) { rs[tid] += rs[tid + s]; is_[tid] += is_[tid + s]; }
    __syncthreads();
  }
  if (tid == 0) {
    A[i * NT + j] = make_float2(rs[0], is_[0]);
    if (i != j) A[j * NT + i] = make_float2(rs[0], -is_[0]);
  }
}

// t = W M;  beta (+)= eta*(M - t).  FIRST: beta is logically zero -> write.
template <bool FIRST>
__global__ void svd_apply_kernel(const float2* __restrict__ M, const float2* __restrict__ Wm,
                                 float2* __restrict__ t, float2* __restrict__ beta,
                                 const float* __restrict__ etap) {
  __shared__ float2 W[NT * NT];
  int tid = threadIdx.x;
  for (int i = tid; i < NT * NT; i += 256) W[i] = Wm[i];
  __syncthreads();
  int p = blockIdx.x * 256 + tid;  // exact: 100*256 == NPIX
  float eta = fmaxf(etap[0], 0.f);
  float2 m[NT];
#pragma unroll
  for (int j = 0; j < NT; ++j) m[j] = M[(size_t)j * NPIX + p];
#pragma unroll
  for (int i = 0; i < NT; ++i) {
    float tr = 0.f, ti = 0.f;
#pragma unroll
    for (int j = 0; j < NT; ++j) {
      float2 w = W[i * NT + j];
      tr += w.x * m[j].x - w.y * m[j].y;
      ti += w.x * m[j].y + w.y * m[j].x;
    }
    t[(size_t)i * NPIX + p] = make_float2(tr, ti);
    if (FIRST) {
      beta[(size_t)i * NPIX + p] = make_float2(eta * (m[i].x - tr), eta * (m[i].y - ti));
    } else {
      float2 b = beta[(size_t)i * NPIX + p];
      b.x += eta * (m[i].x - tr);
      b.y += eta * (m[i].y - ti);
      beta[(size_t)i * NPIX + p] = b;
    }
  }
}

// ---------------------------------------------------------------------------
extern "C" void kernel_launch(void* const* d_in, const int* in_sizes, int n_in,
                              void* d_out, int out_size, void* d_ws, size_t ws_size,
                              hipStream_t stream) {
  // Inputs fp32; mask int32. Output fp32, layout:
  //   out[0 : 460800]                  = real(x_rec)
  //   out[460800 + 921600*i : +921600] = X_SYM[i]
  const float* d_real    = (const float*)d_in[0];
  const float* d_imag    = (const float*)d_in[1];
  const int*   mask      = (const int*)d_in[2];
  const float* W1        = (const float*)d_in[3];
  const float* W2        = (const float*)d_in[4];
  const float* W3        = (const float*)d_in[5];
  const float* W4        = (const float*)d_in[6];
  const float* W5        = (const float*)d_in[7];
  const float* W6        = (const float*)d_in[8];
  const float* lam1      = (const float*)d_in[9];
  const float* lam2      = (const float*)d_in[10];
  const float* soft_thr  = (const float*)d_in[11];
  const float* thres_c   = (const float*)d_in[12];
  const float* eta       = (const float*)d_in[13];
  float* out = (float*)d_out;
  (void)in_sizes; (void)n_in;

  const size_t NEEDED = 74200000ull;
  if (ws_size < NEEDED) {
    probe_kernel<<<(out_size + 255) / 256, 256, 0, stream>>>(out, out_size,
                                                             (float)(ws_size >> 20));
    return;
  }

  char* wp_ = (char*)d_ws;
  auto alloc = [&](size_t bytes) {
    char* r = wp_;
    wp_ += (bytes + 255) & ~(size_t)255;
    return r;
  };
  float2* G      = (float2*)alloc((size_t)NPIX * sizeof(float2));
  float2* xrec   = (float2*)alloc((size_t)NVOX * sizeof(float2));
  float2* tbuf   = (float2*)alloc((size_t)NVOX * sizeof(float2));
  float2* beta   = (float2*)alloc((size_t)NVOX * sizeof(float2));
  float*  Rf     = (float*)alloc((size_t)NVOX * 2 * sizeof(float));
  __half* Af     = (__half*)alloc((size_t)NVOX * 16 * sizeof(__half));
  __half* Bf     = (__half*)alloc((size_t)NVOX * 16 * sizeof(__half));
  __half* Cf     = (__half*)alloc((size_t)NVOX * 16 * sizeof(__half));
  __half* Df     = (__half*)alloc((size_t)NVOX * 16 * sizeof(__half));
  float2* Agram  = (float2*)alloc((size_t)NT * NT * sizeof(float2));
  float2* Wmat   = (float2*)alloc((size_t)NT * NT * sizeof(float2));
  float*  EigScr = (float*)alloc(1296 * sizeof(float));
  float2* T1 = (float2*)Af;
  float2* T2 = (float2*)Bf;

  make_g_kernel<<<100, 256, 0, stream>>>(G);

  // x_rec = ifft2c(mask * d)   (mask_d fused into the first FFT pass)
  fft_pass_last4<1><<<720, 160, 0, stream>>>(nullptr, T2, G, 1, d_real, d_imag, mask);
  fft_pass_mid4<0><<<720, 160, 0, stream>>>(T2, xrec, G, 1, nullptr, nullptr, nullptr,
                                            nullptr, nullptr, nullptr, nullptr, nullptr);

  for (int i = 0; i < 3; ++i) {
    // fft2c(x_rec), fused mask_q; then ifft2c, fused rn -> Rf
    fft_pass_last4<0><<<720, 160, 0, stream>>>(xrec, T1, G, 0, nullptr, nullptr, nullptr);
    fft_pass_mid4<1><<<720, 160, 0, stream>>>(T1, T2, G, 0, d_real, d_imag, mask,
                                              nullptr, nullptr, nullptr, nullptr, nullptr);
    fft_pass_last4<0><<<720, 160, 0, stream>>>(T2, T1, G, 1, nullptr, nullptr, nullptr);
    if (i == 0) {
      fft_pass_mid4<3><<<720, 160, 0, stream>>>(T1, Rf, G, 1, nullptr, nullptr, nullptr,
                                                xrec, nullptr, nullptr, lam1 + i, lam2 + i);
    } else {
      fft_pass_mid4<2><<<720, 160, 0, stream>>>(T1, Rf, G, 1, nullptr, nullptr, nullptr,
                                                xrec, beta, tbuf, lam1 + i, lam2 + i);
    }
    // main conv chain (MFMA throughout)
    conv3d_mfma2in_kernel<true><<<1440, 256, 0, stream>>>(Rf, W1 + (size_t)i * 864, Af);
    conv3d_mfma_kernel<16, true, 1, false, 0, false><<<1440, 256, 0, stream>>>(
        Af, W2 + (size_t)i * 6912, Bf, nullptr, 0.f, nullptr,
        nullptr, nullptr, nullptr, nullptr, nullptr, nullptr, nullptr, 0.f);
    conv3d_mfma_kernel<16, false, 1, false, 0, false><<<1440, 256, 0, stream>>>(
        Bf, W3 + (size_t)i * 6912, Cf, nullptr, 0.f, nullptr,
        nullptr, nullptr, nullptr, nullptr, nullptr, nullptr, nullptr, 0.f);

    if (i < 2) {
      // W4 on soft(x3) (threshold fused into staging); W5; W6 -> xrec
      conv3d_mfma_kernel<16, true, 1, true, 0, false><<<1440, 256, 0, stream>>>(
          Cf, W4 + (size_t)i * 6912, Bf, nullptr, 0.f, soft_thr + i,
          nullptr, nullptr, nullptr, nullptr, nullptr, nullptr, nullptr, 0.f);
      conv3d_mfma_kernel<16, true, 1, false, 0, false><<<1440, 256, 0, stream>>>(
          Bf, W5 + (size_t)i * 6912, Af, nullptr, 0.f, nullptr,
          nullptr, nullptr, nullptr, nullptr, nullptr, nullptr, nullptr, 0.f);
      conv3d_mfma_kernel<2, false, 0, false, 0, false><<<1440, 256, 0, stream>>>(
          Af, W6 + (size_t)i * 864, (float*)xrec, Rf, 1.f, nullptr,
          nullptr, nullptr, nullptr, nullptr, nullptr, nullptr, nullptr, 0.f);
      gram_kernel<<<171, 256, 0, stream>>>((const float2*)xrec, Agram);
      // sym branch with the 1-block Jacobi hidden inside (2 sweeps per part)
      conv3d_mfma_kernel<16, true, 1, false, 1, false><<<1441, 256, 0, stream>>>(
          Cf, W4 + (size_t)i * 6912, Bf, nullptr, 0.f, nullptr,
          Agram, EigScr, thres_c + i, Wmat, nullptr, nullptr, nullptr, 0.f);
      conv3d_mfma_kernel<16, true, 1, false, 2, false><<<1441, 256, 0, stream>>>(
          Bf, W5 + (size_t)i * 6912, Af, nullptr, 0.f, nullptr,
          Agram, EigScr, thres_c + i, Wmat, nullptr, nullptr, nullptr, 0.f);
      conv3d_mfma_kernel<2, false, 0, false, 3, false><<<1441, 256, 0, stream>>>(
          Af, W6 + (size_t)i * 864, out + 460800 + (size_t)921600 * i, Rf, -1.f, nullptr,
          Agram, EigScr, thres_c + i, Wmat, nullptr, nullptr, nullptr, 0.f);
      if (i == 0)
        svd_apply_kernel<true><<<100, 256, 0, stream>>>((const float2*)xrec, Wmat, tbuf, beta, eta + i);
      else
        svd_apply_kernel<false><<<100, 256, 0, stream>>>((const float2*)xrec, Wmat, tbuf, beta, eta + i);
    } else {
      // final iteration: no low-rank step -> main and sym chains are fully
      // independent given Cf/Rf; pair them into 3 double-grid dispatches.
      conv3d_mfma_kernel<16, true, 1, true, 0, true><<<2880, 256, 0, stream>>>(
          Cf, W4 + (size_t)i * 6912, Bf, nullptr, 0.f, soft_thr + i,
          nullptr, nullptr, nullptr, nullptr, nullptr, Cf, Df, 0.f);
      conv3d_mfma_kernel<16, true, 1, false, 0, true><<<2880, 256, 0, stream>>>(
          Bf, W5 + (size_t)i * 6912, Af, nullptr, 0.f, nullptr,
          nullptr, nullptr, nullptr, nullptr, nullptr, Df, Cf, 0.f);
      conv3d_mfma_kernel<2, false, 0, false, 0, true><<<2880, 256, 0, stream>>>(
          Af, W6 + (size_t)i * 864, (float*)xrec, Rf, 1.f, nullptr,
          nullptr, nullptr, nullptr, nullptr, out,
          Cf, out + 460800 + (size_t)921600 * i, -1.f);
    }
  }
}